// Round 1
// baseline (415.056 us; speedup 1.0000x reference)
//
#include <hip/hip_runtime.h>
#include <math.h>

#define NN 512
#define CS 384
#define CZ 128
#define HH 12
#define DQK 16
#define DV 16
#define PQK 4
#define PV 8
#define CATH 176          // DV + PV*3 + PV + CZ = 16+24+8+128
#define CATDIM 2112       // H*CATH

#define SW 0.14433756729740643f     // sqrt(1/(3*16))
#define PW 0.13608276348795434f     // sqrt(1/54)
#define ZW 0.57735026918962576f     // sqrt(1/3)
#define NEG_INF -3.4028234663852886e38f

// ---------------- Kernel A: all linear projections + rotation to global frame
__global__ void proj_kernel(const float* __restrict__ s, const float* __restrict__ rot,
                            const float* __restrict__ tran,
                            const float* __restrict__ Wsq, const float* __restrict__ bsq,
                            const float* __restrict__ Wsk, const float* __restrict__ bsk,
                            const float* __restrict__ Wsv, const float* __restrict__ bsv,
                            const float* __restrict__ Wpq, const float* __restrict__ bpq,
                            const float* __restrict__ Wpk, const float* __restrict__ bpk,
                            const float* __restrict__ Wpv, const float* __restrict__ bpv,
                            float* __restrict__ sq, float* __restrict__ sk, float* __restrict__ sv,
                            float* __restrict__ pqg, float* __restrict__ pkg, float* __restrict__ pvg)
{
    int n = blockIdx.x;
    __shared__ float srow[CS];
    __shared__ float tloc[576];   // pq local 144 | pk local 144 | pv local 288
    __shared__ float R[9], T[3];
    int tid = threadIdx.x;
    for (int k = tid; k < CS; k += 256) srow[k] = s[n * CS + k];
    if (tid < 9) R[tid] = rot[n * 9 + tid];
    if (tid < 3) T[tid] = tran[n * 3 + tid];
    __syncthreads();

    for (int f = tid; f < 1152; f += 256) {
        const float* W; const float* bb; int c; int dout; int seg;
        if (f < 192)      { seg = 0; c = f;       W = Wsq; bb = bsq; dout = 192; }
        else if (f < 384) { seg = 1; c = f - 192; W = Wsk; bb = bsk; dout = 192; }
        else if (f < 576) { seg = 2; c = f - 384; W = Wsv; bb = bsv; dout = 192; }
        else if (f < 720) { seg = 3; c = f - 576; W = Wpq; bb = bpq; dout = 144; }
        else if (f < 864) { seg = 4; c = f - 720; W = Wpk; bb = bpk; dout = 144; }
        else              { seg = 5; c = f - 864; W = Wpv; bb = bpv; dout = 288; }
        float acc = bb[c];
        for (int d = 0; d < CS; d++) acc += srow[d] * W[d * dout + c];
        if (seg == 0)      sq[n * 192 + c] = acc;
        else if (seg == 1) sk[n * 192 + c] = acc;
        else if (seg == 2) sv[n * 192 + c] = acc;
        else if (seg == 3) tloc[c] = acc;
        else if (seg == 4) tloc[144 + c] = acc;
        else               tloc[288 + c] = acc;
    }
    __syncthreads();

    // rotate the 576 point-projection features into global frame
    for (int f = tid; f < 576; f += 256) {
        int seg, base; float* dst;
        if (f < 144)      { seg = f;       base = 0;   dst = pqg + (size_t)n * 144; }
        else if (f < 288) { seg = f - 144; base = 144; dst = pkg + (size_t)n * 144; }
        else              { seg = f - 288; base = 288; dst = pvg + (size_t)n * 288; }
        int x = seg % 3; int hp3 = seg - x;
        float v = R[x * 3 + 0] * tloc[base + hp3 + 0]
                + R[x * 3 + 1] * tloc[base + hp3 + 1]
                + R[x * 3 + 2] * tloc[base + hp3 + 2] + T[x];
        dst[seg] = v;
    }
}

// ---------------- Kernel C: fused attention logits (scalar + point + pair bias)
// grid: (8 j-tiles, 512 i), block 256. z tile staged in LDS, pad stride 132.
__global__ void logits_kernel(const float* __restrict__ z, const float* __restrict__ resm,
                              const float* __restrict__ Wsb, const float* __restrict__ bsb,
                              const float* __restrict__ watt, const float* __restrict__ batt,
                              const float* __restrict__ tpw,
                              const float* __restrict__ sq, const float* __restrict__ sk,
                              const float* __restrict__ pqg, const float* __restrict__ pkg,
                              float* __restrict__ logits)
{
    int i  = blockIdx.y;
    int j0 = blockIdx.x * 64;
    __shared__ float zt[64 * 132];
    __shared__ float wsbs[128 * 12];
    __shared__ float sqs[192];
    __shared__ float pqi[144];
    __shared__ float cpt[12];
    __shared__ float cb[12];
    int tid = threadIdx.x;
    float w0 = watt[0], w1 = watt[1], w2 = watt[2], ba = batt[0];
    float A2 = w2 * ZW;

    // stage z tile [64][128] -> zt with pad 132 (float4, aligned)
    const float4* z4 = (const float4*)(z + ((size_t)i * NN + j0) * CZ);
    for (int k = tid; k < 2048; k += 256) {
        int j = k >> 5; int c4 = k & 31;
        float4 v = z4[k];
        *(float4*)&zt[j * 132 + c4 * 4] = v;
    }
    for (int k = tid; k < 1536; k += 256) wsbs[k] = Wsb[k] * A2;
    for (int k = tid; k < 192; k += 256)  sqs[k] = sq[(size_t)i * 192 + k] * (SW * w0);
    if (tid < 144) pqi[tid] = pqg[(size_t)i * 144 + tid];
    if (tid < 12) {
        cpt[tid] = -0.5f * log1pf(expf(tpw[tid])) * PW * w1;
        cb[tid]  = A2 * bsb[tid] + ba;
    }
    __syncthreads();

    int jl = tid >> 2, hg = tid & 3;
    int j = j0 + jl;
    int h0 = hg * 3;
    float mj = resm[i] * resm[j];

    // pair term: z row (LDS) dot scaled Wsb columns
    float acc0 = cb[h0], acc1 = cb[h0 + 1], acc2 = cb[h0 + 2];
    const float* zrow = &zt[jl * 132];
    #pragma unroll 4
    for (int c = 0; c < 128; c++) {
        float zv = zrow[c];
        acc0 += zv * wsbs[c * 12 + h0];
        acc1 += zv * wsbs[c * 12 + h0 + 1];
        acc2 += zv * wsbs[c * 12 + h0 + 2];
    }

    #pragma unroll
    for (int hhh = 0; hhh < 3; hhh++) {
        int h = h0 + hhh;
        // scalar term
        const float4* skp = (const float4*)(sk + ((size_t)j * HH + h) * DQK);
        const float* sqp = &sqs[h * 16];
        float d0 = 0.f;
        #pragma unroll
        for (int q = 0; q < 4; q++) {
            float4 kv = skp[q];
            d0 += sqp[q*4+0]*kv.x + sqp[q*4+1]*kv.y + sqp[q*4+2]*kv.z + sqp[q*4+3]*kv.w;
        }
        // point distance term
        const float4* pkp = (const float4*)(pkg + ((size_t)j * HH + h) * 12);
        const float* pqp = &pqi[h * 12];
        float sd = 0.f;
        #pragma unroll
        for (int q = 0; q < 3; q++) {
            float4 kv = pkp[q];
            float a = pqp[q*4+0]-kv.x, b = pqp[q*4+1]-kv.y, c = pqp[q*4+2]-kv.z, e = pqp[q*4+3]-kv.w;
            sd += a*a + b*b + c*c + e*e;
        }
        float pairv = (hhh == 0) ? acc0 : ((hhh == 1) ? acc1 : acc2);
        float lg = pairv + d0 + cpt[h] * sd;
        if (mj == 0.f) lg = NEG_INF;
        logits[((size_t)i * HH + h) * NN + j] = lg;
    }
}

// ---------------- Kernel D: softmax over j + all attention-weighted sums + cat assembly
// one block per i
__global__ void attn_sum_kernel(const float* __restrict__ z, const float* __restrict__ sv,
                                const float* __restrict__ pvg, const float* __restrict__ rot,
                                const float* __restrict__ tran, const float* __restrict__ logits,
                                float* __restrict__ cat)
{
    int i = blockIdx.x;
    __shared__ float at[HH * NN];   // 24.6 KB
    __shared__ float rpt[288];
    int tid = threadIdx.x;

    const float4* lg4 = (const float4*)(logits + (size_t)i * HH * NN);
    float4* at4 = (float4*)at;
    for (int k = tid; k < HH * NN / 4; k += 256) at4[k] = lg4[k];
    __syncthreads();

    // softmax: wave w handles heads w, w+4, w+8
    int wid = tid >> 6, lane = tid & 63;
    for (int t = 0; t < 3; t++) {
        int h = wid + 4 * t;
        float* row = &at[h * NN];
        float v[8]; float m = -INFINITY;
        #pragma unroll
        for (int u = 0; u < 8; u++) { v[u] = row[lane + 64 * u]; m = fmaxf(m, v[u]); }
        for (int off = 32; off; off >>= 1) m = fmaxf(m, __shfl_xor(m, off));
        float ssum = 0.f;
        #pragma unroll
        for (int u = 0; u < 8; u++) { v[u] = __expf(v[u] - m); ssum += v[u]; }
        for (int off = 32; off; off >>= 1) ssum += __shfl_xor(ssum, off);
        float inv = 1.f / ssum;
        #pragma unroll
        for (int u = 0; u < 8; u++) row[lane + 64 * u] = v[u] * inv;
    }
    __syncthreads();

    // r_pair: thread -> (h-group of 6, channel c); z read coalesced
    {
        int c = tid & 127; int hbase = (tid >> 7) * 6;
        float acc[6] = {0,0,0,0,0,0};
        const float* zp = z + (size_t)i * NN * CZ + c;
        #pragma unroll 4
        for (int j = 0; j < NN; j++) {
            float zv = zp[(size_t)j * CZ];
            #pragma unroll
            for (int hh2 = 0; hh2 < 6; hh2++) acc[hh2] += zv * at[(hbase + hh2) * NN + j];
        }
        float* cp = cat + (size_t)i * CATDIM;
        #pragma unroll
        for (int hh2 = 0; hh2 < 6; hh2++) cp[(hbase + hh2) * CATH + 48 + c] = acc[hh2];
    }

    // r_scalar: threads 0..191 -> (h, d)
    if (tid < 192) {
        int h = tid >> 4, d = tid & 15;
        float acc = 0.f;
        const float* svp = sv + h * 16 + d;
        #pragma unroll 4
        for (int j = 0; j < NN; j++) acc += at[h * NN + j] * svp[(size_t)j * 192];
        cat[(size_t)i * CATDIM + h * CATH + d] = acc;
    }

    // r_pt global-frame sums: 288 features
    for (int f = tid; f < 288; f += 256) {
        int h = f / 24, pc = f % 24;
        float acc = 0.f;
        const float* pvp = pvg + h * 24 + pc;
        #pragma unroll 4
        for (int j = 0; j < NN; j++) acc += at[h * NN + j] * pvp[(size_t)j * 288];
        rpt[f] = acc;
    }
    __syncthreads();

    // rotate back to local frame, norms, write pt + norm slices of cat
    if (tid < 96) {
        int h = tid / 8, p = tid % 8;
        float gx = rpt[h * 24 + p * 3 + 0] - tran[i * 3 + 0];
        float gy = rpt[h * 24 + p * 3 + 1] - tran[i * 3 + 1];
        float gz = rpt[h * 24 + p * 3 + 2] - tran[i * 3 + 2];
        const float* R = rot + i * 9;
        float lx = R[0] * gx + R[3] * gy + R[6] * gz;   // out[x] = sum_y rot[y][x] g[y]
        float ly = R[1] * gx + R[4] * gy + R[7] * gz;
        float lz = R[2] * gx + R[5] * gy + R[8] * gz;
        float nrm = sqrtf(lx * lx + ly * ly + lz * lz + 1e-8f);
        float* cp = cat + (size_t)i * CATDIM + h * CATH;
        cp[16 + p * 3 + 0] = lx; cp[16 + p * 3 + 1] = ly; cp[16 + p * 3 + 2] = lz;
        cp[40 + p] = nrm;
    }
}

// ---------------- Kernel E: out = cat[512,2112] @ Wout[2112,384] + bout
__global__ void out_gemm_kernel(const float* __restrict__ cat, const float* __restrict__ Wout,
                                const float* __restrict__ bout, float* __restrict__ out)
{
    __shared__ float As[32][33];
    __shared__ float Bs[32][33];
    int tid = threadIdx.x;
    int tx = tid & 15, ty = tid >> 4;
    int n0 = blockIdx.x * 32;
    int i0 = blockIdx.y * 32;
    float acc00 = 0, acc01 = 0, acc10 = 0, acc11 = 0;
    for (int k0 = 0; k0 < CATDIM; k0 += 32) {
        for (int e = tid; e < 1024; e += 256) {
            int r = e >> 5, c = e & 31;
            As[r][c] = cat[(size_t)(i0 + r) * CATDIM + k0 + c];
            Bs[r][c] = Wout[(size_t)(k0 + r) * CS + n0 + c];
        }
        __syncthreads();
        #pragma unroll
        for (int k = 0; k < 32; k++) {
            float a0 = As[ty * 2][k], a1 = As[ty * 2 + 1][k];
            float b0 = Bs[k][tx * 2], b1 = Bs[k][tx * 2 + 1];
            acc00 += a0 * b0; acc01 += a0 * b1;
            acc10 += a1 * b0; acc11 += a1 * b1;
        }
        __syncthreads();
    }
    out[(size_t)(i0 + ty * 2 + 0) * CS + n0 + tx * 2 + 0] = acc00 + bout[n0 + tx * 2 + 0];
    out[(size_t)(i0 + ty * 2 + 0) * CS + n0 + tx * 2 + 1] = acc01 + bout[n0 + tx * 2 + 1];
    out[(size_t)(i0 + ty * 2 + 1) * CS + n0 + tx * 2 + 0] = acc10 + bout[n0 + tx * 2 + 0];
    out[(size_t)(i0 + ty * 2 + 1) * CS + n0 + tx * 2 + 1] = acc11 + bout[n0 + tx * 2 + 1];
}

extern "C" void kernel_launch(void* const* d_in, const int* in_sizes, int n_in,
                              void* d_out, int out_size, void* d_ws, size_t ws_size,
                              hipStream_t stream) {
    const float* s    = (const float*)d_in[0];
    const float* z    = (const float*)d_in[1];
    const float* rot  = (const float*)d_in[2];
    const float* tran = (const float*)d_in[3];
    const float* resm = (const float*)d_in[4];
    const float* Wsq  = (const float*)d_in[5];  const float* bsq = (const float*)d_in[6];
    const float* Wsk  = (const float*)d_in[7];  const float* bsk = (const float*)d_in[8];
    const float* Wsv  = (const float*)d_in[9];  const float* bsv = (const float*)d_in[10];
    const float* Wsb  = (const float*)d_in[11]; const float* bsb = (const float*)d_in[12];
    const float* Wpq  = (const float*)d_in[13]; const float* bpq = (const float*)d_in[14];
    const float* Wpk  = (const float*)d_in[15]; const float* bpk = (const float*)d_in[16];
    const float* Wpv  = (const float*)d_in[17]; const float* bpv = (const float*)d_in[18];
    const float* watt = (const float*)d_in[19]; const float* batt = (const float*)d_in[20];
    const float* tpw  = (const float*)d_in[21];
    const float* Wout = (const float*)d_in[22]; const float* bout = (const float*)d_in[23];
    float* out = (float*)d_out;
    float* ws  = (float*)d_ws;

    float* sq     = ws;                 // 512*192
    float* sk     = sq  + 98304;        // 512*192
    float* sv     = sk  + 98304;        // 512*192
    float* pqg    = sv  + 98304;        // 512*144
    float* pkg    = pqg + 73728;        // 512*144
    float* pvg    = pkg + 73728;        // 512*288
    float* logits = pvg + 147456;       // 512*12*512
    float* cat    = logits + 3145728;   // 512*2112

    proj_kernel<<<512, 256, 0, stream>>>(s, rot, tran, Wsq, bsq, Wsk, bsk, Wsv, bsv,
                                         Wpq, bpq, Wpk, bpk, Wpv, bpv,
                                         sq, sk, sv, pqg, pkg, pvg);
    logits_kernel<<<dim3(8, 512), 256, 0, stream>>>(z, resm, Wsb, bsb, watt, batt, tpw,
                                                    sq, sk, pqg, pkg, logits);
    attn_sum_kernel<<<512, 256, 0, stream>>>(z, sv, pvg, rot, tran, logits, cat);
    out_gemm_kernel<<<dim3(12, 16), 256, 0, stream>>>(cat, Wout, bout, out);
}

// Round 2
// 237.228 us; speedup vs baseline: 1.7496x; 1.7496x over previous
//
#include <hip/hip_runtime.h>
#include <math.h>

#define NN 512
#define CSD 384
#define CZ 128
#define HH 12
#define TMPW 1152          // 192 sq | 192 sk | 192 sv | 144 pq | 144 pk | 288 pv
#define CATH 176
#define CATDIM 2112
#define NSPLIT 6
#define KSPL 352

#define SW 0.14433756729740643f
#define PW 0.13608276348795434f
#define ZW 0.57735026918962576f
#define NEG_INF -3.4028234663852886e38f

// ---------------- proj GEMM: tmp[512][1152] = s[512][384] @ Wcat + bias
// f-tiles of 48 always lie within one weight segment.
__global__ void proj_gemm_kernel(const float* __restrict__ s,
                                 const float* __restrict__ Wsq, const float* __restrict__ bsq,
                                 const float* __restrict__ Wsk, const float* __restrict__ bsk,
                                 const float* __restrict__ Wsv, const float* __restrict__ bsv,
                                 const float* __restrict__ Wpq, const float* __restrict__ bpq,
                                 const float* __restrict__ Wpk, const float* __restrict__ bpk,
                                 const float* __restrict__ Wpv, const float* __restrict__ bpv,
                                 float* __restrict__ tmp)
{
    int bx = blockIdx.x;            // 24 f-tiles
    int n0 = blockIdx.y * 32;       // 16 n-tiles
    int f0 = bx * 48;
    const float* W; const float* bb; int dout; int segstart;
    if (bx < 4)       { W = Wsq; bb = bsq; dout = 192; segstart = 0; }
    else if (bx < 8)  { W = Wsk; bb = bsk; dout = 192; segstart = 192; }
    else if (bx < 12) { W = Wsv; bb = bsv; dout = 192; segstart = 384; }
    else if (bx < 15) { W = Wpq; bb = bpq; dout = 144; segstart = 576; }
    else if (bx < 18) { W = Wpk; bb = bpk; dout = 144; segstart = 720; }
    else              { W = Wpv; bb = bpv; dout = 288; segstart = 864; }
    int colbase = f0 - segstart;

    __shared__ float St[32][34];    // s-tile transposed [k][n]
    __shared__ float Ws[32][49];    // W-tile [k][f]
    int tid = threadIdx.x;
    int ty = tid >> 4, tx = tid & 15;   // rows ty*2.., cols tx*3..
    float acc[2][3] = {{0,0,0},{0,0,0}};

    for (int k0 = 0; k0 < CSD; k0 += 32) {
        {
            int r = tid >> 3, c4 = (tid & 7) * 4;
            float4 v = *(const float4*)&s[(size_t)(n0 + r) * CSD + k0 + c4];
            St[c4 + 0][r] = v.x; St[c4 + 1][r] = v.y; St[c4 + 2][r] = v.z; St[c4 + 3][r] = v.w;
        }
        for (int e = tid; e < 1536; e += 256) {
            int r = e / 48, c = e % 48;
            Ws[r][c] = W[(size_t)(k0 + r) * dout + colbase + c];
        }
        __syncthreads();
        #pragma unroll
        for (int k = 0; k < 32; k++) {
            float2 a = *(const float2*)&St[k][ty * 2];
            float b0 = Ws[k][tx * 3], b1 = Ws[k][tx * 3 + 1], b2 = Ws[k][tx * 3 + 2];
            acc[0][0] += a.x * b0; acc[0][1] += a.x * b1; acc[0][2] += a.x * b2;
            acc[1][0] += a.y * b0; acc[1][1] += a.y * b1; acc[1][2] += a.y * b2;
        }
        __syncthreads();
    }
    float bv0 = bb[colbase + tx * 3], bv1 = bb[colbase + tx * 3 + 1], bv2 = bb[colbase + tx * 3 + 2];
    #pragma unroll
    for (int r = 0; r < 2; r++) {
        float* o = tmp + (size_t)(n0 + ty * 2 + r) * TMPW + f0 + tx * 3;
        o[0] = acc[r][0] + bv0; o[1] = acc[r][1] + bv1; o[2] = acc[r][2] + bv2;
    }
}

// ---------------- rotate point projections to global frame, in place on tmp
__global__ void rotate_kernel(const float* __restrict__ rot, const float* __restrict__ tran,
                              float* __restrict__ tmp)
{
    int pid = blockIdx.x * 256 + threadIdx.x;   // 512*192 points
    int n = pid / 192, q = pid % 192;
    float* p = tmp + (size_t)n * TMPW + 576 + q * 3;
    float v0 = p[0], v1 = p[1], v2 = p[2];
    const float* R = rot + n * 9;
    const float* T = tran + n * 3;
    p[0] = R[0] * v0 + R[1] * v1 + R[2] * v2 + T[0];
    p[1] = R[3] * v0 + R[4] * v1 + R[5] * v2 + T[1];
    p[2] = R[6] * v0 + R[7] * v1 + R[8] * v2 + T[2];
}

// ---------------- fused logits: scalar + point + pair bias -> logits[i][h][j]
__global__ void logits_kernel(const float* __restrict__ z, const float* __restrict__ resm,
                              const float* __restrict__ Wsb, const float* __restrict__ bsb,
                              const float* __restrict__ watt, const float* __restrict__ batt,
                              const float* __restrict__ tpw, const float* __restrict__ tmp,
                              float* __restrict__ logits)
{
    int i  = blockIdx.y;
    int j0 = blockIdx.x * 64;
    __shared__ float zt[64 * 132];
    __shared__ float wsbsT[12 * 128];
    __shared__ float sqs[192];
    __shared__ float pqi[144];
    __shared__ float cpt[12];
    __shared__ float cb[12];
    int tid = threadIdx.x;
    float w0 = watt[0], w1 = watt[1], w2 = watt[2], ba = batt[0];
    float A2 = w2 * ZW;

    const float4* z4 = (const float4*)(z + ((size_t)i * NN + j0) * CZ);
    for (int k = tid; k < 2048; k += 256) {
        int j = k >> 5; int c4 = k & 31;
        *(float4*)&zt[j * 132 + c4 * 4] = z4[k];
    }
    for (int k = tid; k < 1536; k += 256) {
        int h = k >> 7, c = k & 127;
        wsbsT[k] = Wsb[c * 12 + h] * A2;
    }
    for (int k = tid; k < 192; k += 256) sqs[k] = tmp[(size_t)i * TMPW + k] * (SW * w0);
    if (tid < 144) pqi[tid] = tmp[(size_t)i * TMPW + 576 + tid];
    if (tid < 12) {
        cpt[tid] = -0.5f * log1pf(expf(tpw[tid])) * PW * w1;
        cb[tid]  = A2 * bsb[tid] + ba;
    }
    __syncthreads();

    int jl = tid >> 2, hg = tid & 3;
    int j = j0 + jl;
    int h0 = hg * 3;
    float mj = resm[i] * resm[j];

    float p0 = cb[h0], p1 = cb[h0 + 1], p2 = cb[h0 + 2];
    const float* zr = &zt[jl * 132];
    const float* wa = &wsbsT[(h0 + 0) * 128];
    const float* wb = &wsbsT[(h0 + 1) * 128];
    const float* wc = &wsbsT[(h0 + 2) * 128];
    #pragma unroll 8
    for (int c = 0; c < 128; c += 4) {
        float4 zv = *(const float4*)&zr[c];
        float4 a = *(const float4*)&wa[c];
        float4 b = *(const float4*)&wb[c];
        float4 cc = *(const float4*)&wc[c];
        p0 += zv.x * a.x + zv.y * a.y + zv.z * a.z + zv.w * a.w;
        p1 += zv.x * b.x + zv.y * b.y + zv.z * b.z + zv.w * b.w;
        p2 += zv.x * cc.x + zv.y * cc.y + zv.z * cc.z + zv.w * cc.w;
    }

    #pragma unroll
    for (int hhh = 0; hhh < 3; hhh++) {
        int h = h0 + hhh;
        const float4* skp = (const float4*)(tmp + (size_t)j * TMPW + 192 + h * 16);
        const float* sqp = &sqs[h * 16];
        float d0 = 0.f;
        #pragma unroll
        for (int q = 0; q < 4; q++) {
            float4 kv = skp[q];
            d0 += sqp[q*4+0]*kv.x + sqp[q*4+1]*kv.y + sqp[q*4+2]*kv.z + sqp[q*4+3]*kv.w;
        }
        const float4* pkp = (const float4*)(tmp + (size_t)j * TMPW + 720 + h * 12);
        const float* pqp = &pqi[h * 12];
        float sd = 0.f;
        #pragma unroll
        for (int q = 0; q < 3; q++) {
            float4 kv = pkp[q];
            float a = pqp[q*4+0]-kv.x, b = pqp[q*4+1]-kv.y, c = pqp[q*4+2]-kv.z, e = pqp[q*4+3]-kv.w;
            sd += a*a + b*b + c*c + e*e;
        }
        float pairv = (hhh == 0) ? p0 : ((hhh == 1) ? p1 : p2);
        float lg = pairv + d0 + cpt[h] * sd;
        if (mj == 0.f) lg = NEG_INF;
        logits[((size_t)i * HH + h) * NN + j] = lg;
    }
}

// ---------------- softmax (in-place logits->attn) + r_pair
__global__ void softmax_rpair_kernel(const float* __restrict__ z, float* __restrict__ attn,
                                     float* __restrict__ cat)
{
    int i = blockIdx.x;
    __shared__ float at[HH * NN];
    int tid = threadIdx.x;
    float4* at4 = (float4*)at;
    {
        const float4* lg4 = (const float4*)(attn + (size_t)i * HH * NN);
        for (int k = tid; k < HH * NN / 4; k += 256) at4[k] = lg4[k];
    }
    __syncthreads();

    int wid = tid >> 6, lane = tid & 63;
    for (int t = 0; t < 3; t++) {
        int h = wid + 4 * t;
        float* row = &at[h * NN];
        float v[8]; float m = -INFINITY;
        #pragma unroll
        for (int u = 0; u < 8; u++) { v[u] = row[lane + 64 * u]; m = fmaxf(m, v[u]); }
        for (int off = 32; off; off >>= 1) m = fmaxf(m, __shfl_xor(m, off));
        float ssum = 0.f;
        #pragma unroll
        for (int u = 0; u < 8; u++) { v[u] = __expf(v[u] - m); ssum += v[u]; }
        for (int off = 32; off; off >>= 1) ssum += __shfl_xor(ssum, off);
        float inv = 1.f / ssum;
        #pragma unroll
        for (int u = 0; u < 8; u++) row[lane + 64 * u] = v[u] * inv;
    }
    __syncthreads();

    // write normalized attn back to global (for head_sum kernel)
    {
        float4* ag = (float4*)(attn + (size_t)i * HH * NN);
        for (int k = tid; k < HH * NN / 4; k += 256) ag[k] = at4[k];
    }

    // r_pair: wave w -> heads 3w..3w+2; lane -> channels lane, lane+64
    int h0 = wid * 3;
    const float* zrow = z + (size_t)i * NN * CZ;
    float acc[3][2] = {{0,0},{0,0},{0,0}};
    for (int j = 0; j < NN; j += 4) {
        float4 a0 = *(const float4*)&at[(h0 + 0) * NN + j];
        float4 a1 = *(const float4*)&at[(h0 + 1) * NN + j];
        float4 a2 = *(const float4*)&at[(h0 + 2) * NN + j];
        float A0[4] = {a0.x, a0.y, a0.z, a0.w};
        float A1[4] = {a1.x, a1.y, a1.z, a1.w};
        float A2v[4] = {a2.x, a2.y, a2.z, a2.w};
        #pragma unroll
        for (int q = 0; q < 4; q++) {
            float z0 = zrow[(size_t)(j + q) * CZ + lane];
            float z1 = zrow[(size_t)(j + q) * CZ + lane + 64];
            acc[0][0] += A0[q] * z0; acc[0][1] += A0[q] * z1;
            acc[1][0] += A1[q] * z0; acc[1][1] += A1[q] * z1;
            acc[2][0] += A2v[q] * z0; acc[2][1] += A2v[q] * z1;
        }
    }
    #pragma unroll
    for (int t = 0; t < 3; t++) {
        cat[(size_t)i * CATDIM + (h0 + t) * CATH + 48 + lane]      = acc[t][0];
        cat[(size_t)i * CATDIM + (h0 + t) * CATH + 48 + lane + 64] = acc[t][1];
    }
}

// ---------------- per-head r_scalar + r_pt (+rotate back, norm): block = (i-tile 32, h)
__global__ void head_sum_kernel(const float* __restrict__ attn, const float* __restrict__ tmp,
                                const float* __restrict__ rot, const float* __restrict__ tran,
                                float* __restrict__ cat)
{
    int i0 = blockIdx.x * 32;   // 16 tiles
    int h  = blockIdx.y;        // 12
    __shared__ float At[32][65];
    __shared__ float Sr[64][44];
    __shared__ float Rp[32][24];
    int tid = threadIdx.x;
    int il = tid & 31, fg = tid >> 5;        // feats fg*5 .. fg*5+4
    float acc[5] = {0,0,0,0,0};

    for (int jc = 0; jc < NN; jc += 64) {
        {
            int r = tid >> 3, c8 = (tid & 7) * 8;
            const float* src = attn + ((size_t)(i0 + r) * HH + h) * NN + jc + c8;
            float4 v0 = *(const float4*)src;
            float4 v1 = *(const float4*)(src + 4);
            At[r][c8+0]=v0.x; At[r][c8+1]=v0.y; At[r][c8+2]=v0.z; At[r][c8+3]=v0.w;
            At[r][c8+4]=v1.x; At[r][c8+5]=v1.y; At[r][c8+6]=v1.z; At[r][c8+7]=v1.w;
        }
        {
            int jr = tid >> 2, d4 = (tid & 3) * 4;
            *(float4*)&Sr[jr][d4] = *(const float4*)&tmp[(size_t)(jc + jr) * TMPW + 384 + h * 16 + d4];
        }
        for (int e = tid; e < 384; e += 256) {
            int jr = e / 6, p4 = (e % 6) * 4;
            *(float4*)&Sr[jr][16 + p4] = *(const float4*)&tmp[(size_t)(jc + jr) * TMPW + 864 + h * 24 + p4];
        }
        __syncthreads();
        #pragma unroll 4
        for (int j = 0; j < 64; j++) {
            float a = At[il][j];
            #pragma unroll
            for (int q = 0; q < 5; q++) acc[q] += a * Sr[j][fg * 5 + q];
        }
        __syncthreads();
    }

    float* cbase = cat + (size_t)(i0 + il) * CATDIM + h * CATH;
    #pragma unroll
    for (int q = 0; q < 5; q++) {
        int f = fg * 5 + q;
        if (f < 16) cbase[f] = acc[q];
        else Rp[il][f - 16] = acc[q];
    }
    __syncthreads();

    {
        int il2 = tid >> 3, p = tid & 7;
        int i = i0 + il2;
        float gx = Rp[il2][p * 3 + 0] - tran[i * 3 + 0];
        float gy = Rp[il2][p * 3 + 1] - tran[i * 3 + 1];
        float gz = Rp[il2][p * 3 + 2] - tran[i * 3 + 2];
        const float* R = rot + i * 9;
        float lx = R[0] * gx + R[3] * gy + R[6] * gz;
        float ly = R[1] * gx + R[4] * gy + R[7] * gz;
        float lz = R[2] * gx + R[5] * gy + R[8] * gz;
        float nrm = sqrtf(lx * lx + ly * ly + lz * lz + 1e-8f);
        float* cp = cat + (size_t)i * CATDIM + h * CATH;
        cp[16 + p * 3 + 0] = lx; cp[16 + p * 3 + 1] = ly; cp[16 + p * 3 + 2] = lz;
        cp[40 + p] = nrm;
    }
}

// ---------------- out GEMM, K-split: part[s][512][384]
__global__ void out_gemm_split_kernel(const float* __restrict__ cat, const float* __restrict__ Wout,
                                      float* __restrict__ part)
{
    int n0 = blockIdx.x * 64;       // 6
    int i0 = blockIdx.y * 64;       // 8
    int ks = blockIdx.z * KSPL;     // 6 splits of 352
    __shared__ float St[32][68];
    __shared__ float Bs[32][68];
    int tid = threadIdx.x;
    int ty = tid >> 4, tx = tid & 15;   // rows ty*4.., cols tx*4..
    float acc[4][4] = {{0,0,0,0},{0,0,0,0},{0,0,0,0},{0,0,0,0}};

    for (int k0 = 0; k0 < KSPL; k0 += 32) {
        {
            int r = tid >> 2, c8 = (tid & 3) * 8;
            const float* src = cat + (size_t)(i0 + r) * CATDIM + ks + k0 + c8;
            float4 v0 = *(const float4*)src;
            float4 v1 = *(const float4*)(src + 4);
            St[c8+0][r]=v0.x; St[c8+1][r]=v0.y; St[c8+2][r]=v0.z; St[c8+3][r]=v0.w;
            St[c8+4][r]=v1.x; St[c8+5][r]=v1.y; St[c8+6][r]=v1.z; St[c8+7][r]=v1.w;
        }
        {
            int r = tid >> 3, c8 = (tid & 7) * 8;
            const float* src = Wout + (size_t)(ks + k0 + r) * CSD + n0 + c8;
            *(float4*)&Bs[r][c8]     = *(const float4*)src;
            *(float4*)&Bs[r][c8 + 4] = *(const float4*)(src + 4);
        }
        __syncthreads();
        #pragma unroll
        for (int k = 0; k < 32; k++) {
            float4 a = *(const float4*)&St[k][ty * 4];
            float4 b = *(const float4*)&Bs[k][tx * 4];
            float av[4] = {a.x, a.y, a.z, a.w};
            float bv[4] = {b.x, b.y, b.z, b.w};
            #pragma unroll
            for (int r = 0; r < 4; r++)
                #pragma unroll
                for (int c = 0; c < 4; c++) acc[r][c] += av[r] * bv[c];
        }
        __syncthreads();
    }
    #pragma unroll
    for (int r = 0; r < 4; r++) {
        float4 v = make_float4(acc[r][0], acc[r][1], acc[r][2], acc[r][3]);
        *(float4*)&part[((size_t)blockIdx.z * NN + i0 + ty * 4 + r) * CSD + n0 + tx * 4] = v;
    }
}

__global__ void reduce_out_kernel(const float* __restrict__ part, const float* __restrict__ bout,
                                  float* __restrict__ out)
{
    int v = blockIdx.x * 256 + threadIdx.x;     // 49152 float4 slots
    int n4 = v % 96;
    float4 o = ((const float4*)bout)[n4];
    const float4* p4 = (const float4*)part;
    #pragma unroll
    for (int s = 0; s < NSPLIT; s++) {
        float4 t = p4[(size_t)s * 49152 + v];
        o.x += t.x; o.y += t.y; o.z += t.z; o.w += t.w;
    }
    ((float4*)out)[v] = o;
}

extern "C" void kernel_launch(void* const* d_in, const int* in_sizes, int n_in,
                              void* d_out, int out_size, void* d_ws, size_t ws_size,
                              hipStream_t stream) {
    const float* s    = (const float*)d_in[0];
    const float* z    = (const float*)d_in[1];
    const float* rot  = (const float*)d_in[2];
    const float* tran = (const float*)d_in[3];
    const float* resm = (const float*)d_in[4];
    const float* Wsq  = (const float*)d_in[5];  const float* bsq = (const float*)d_in[6];
    const float* Wsk  = (const float*)d_in[7];  const float* bsk = (const float*)d_in[8];
    const float* Wsv  = (const float*)d_in[9];  const float* bsv = (const float*)d_in[10];
    const float* Wsb  = (const float*)d_in[11]; const float* bsb = (const float*)d_in[12];
    const float* Wpq  = (const float*)d_in[13]; const float* bpq = (const float*)d_in[14];
    const float* Wpk  = (const float*)d_in[15]; const float* bpk = (const float*)d_in[16];
    const float* Wpv  = (const float*)d_in[17]; const float* bpv = (const float*)d_in[18];
    const float* watt = (const float*)d_in[19]; const float* batt = (const float*)d_in[20];
    const float* tpw  = (const float*)d_in[21];
    const float* Wout = (const float*)d_in[22]; const float* bout = (const float*)d_in[23];
    float* out = (float*)d_out;
    float* ws  = (float*)d_ws;

    float* tmp    = ws;                    // 512*1152   = 589824
    float* logits = tmp + 589824;          // 512*12*512 = 3145728 (becomes attn in-place)
    float* cat    = logits + 3145728;      // 512*2112   = 1081344
    float* part   = cat + 1081344;         // 6*512*384  = 1179648

    proj_gemm_kernel<<<dim3(24, 16), 256, 0, stream>>>(s, Wsq, bsq, Wsk, bsk, Wsv, bsv,
                                                       Wpq, bpq, Wpk, bpk, Wpv, bpv, tmp);
    rotate_kernel<<<384, 256, 0, stream>>>(rot, tran, tmp);
    logits_kernel<<<dim3(8, 512), 256, 0, stream>>>(z, resm, Wsb, bsb, watt, batt, tpw,
                                                    tmp, logits);
    softmax_rpair_kernel<<<512, 256, 0, stream>>>(z, logits, cat);
    head_sum_kernel<<<dim3(16, 12), 256, 0, stream>>>(logits, tmp, rot, tran, cat);
    out_gemm_split_kernel<<<dim3(6, 8, NSPLIT), 256, 0, stream>>>(cat, Wout, part);
    reduce_out_kernel<<<192, 256, 0, stream>>>(part, bout, out);
}

// Round 3
// 205.153 us; speedup vs baseline: 2.0232x; 1.1563x over previous
//
#include <hip/hip_runtime.h>
#include <math.h>

#define NN 512
#define CSD 384
#define CZ 128
#define HH 12
#define TMPW 1152          // 192 sq | 192 sk | 192 sv | 144 pq | 144 pk | 288 pv
#define CATH 176
#define CATDIM 2112
#define NSPLIT 6
#define KSPL 352

#define SW 0.14433756729740643f
#define PW 0.13608276348795434f
#define ZW 0.57735026918962576f
#define NEG_INF -3.4028234663852886e38f

// ---------------- proj GEMM: tmp[512][1152] = s[512][384] @ Wcat + bias
__global__ void proj_gemm_kernel(const float* __restrict__ s,
                                 const float* __restrict__ Wsq, const float* __restrict__ bsq,
                                 const float* __restrict__ Wsk, const float* __restrict__ bsk,
                                 const float* __restrict__ Wsv, const float* __restrict__ bsv,
                                 const float* __restrict__ Wpq, const float* __restrict__ bpq,
                                 const float* __restrict__ Wpk, const float* __restrict__ bpk,
                                 const float* __restrict__ Wpv, const float* __restrict__ bpv,
                                 float* __restrict__ tmp)
{
    int bx = blockIdx.x;            // 24 f-tiles of 48
    int n0 = blockIdx.y * 32;       // 16 n-tiles
    int f0 = bx * 48;
    const float* W; const float* bb; int dout; int segstart;
    if (bx < 4)       { W = Wsq; bb = bsq; dout = 192; segstart = 0; }
    else if (bx < 8)  { W = Wsk; bb = bsk; dout = 192; segstart = 192; }
    else if (bx < 12) { W = Wsv; bb = bsv; dout = 192; segstart = 384; }
    else if (bx < 15) { W = Wpq; bb = bpq; dout = 144; segstart = 576; }
    else if (bx < 18) { W = Wpk; bb = bpk; dout = 144; segstart = 720; }
    else              { W = Wpv; bb = bpv; dout = 288; segstart = 864; }
    int colbase = f0 - segstart;

    __shared__ float St[32][34];
    __shared__ float Ws[32][49];
    int tid = threadIdx.x;
    int ty = tid >> 4, tx = tid & 15;
    float acc[2][3] = {{0,0,0},{0,0,0}};

    for (int k0 = 0; k0 < CSD; k0 += 32) {
        {
            int r = tid >> 3, c4 = (tid & 7) * 4;
            float4 v = *(const float4*)&s[(size_t)(n0 + r) * CSD + k0 + c4];
            St[c4 + 0][r] = v.x; St[c4 + 1][r] = v.y; St[c4 + 2][r] = v.z; St[c4 + 3][r] = v.w;
        }
        for (int e = tid; e < 1536; e += 256) {
            int r = e / 48, c = e % 48;
            Ws[r][c] = W[(size_t)(k0 + r) * dout + colbase + c];
        }
        __syncthreads();
        #pragma unroll
        for (int k = 0; k < 32; k++) {
            float2 a = *(const float2*)&St[k][ty * 2];
            float b0 = Ws[k][tx * 3], b1 = Ws[k][tx * 3 + 1], b2 = Ws[k][tx * 3 + 2];
            acc[0][0] += a.x * b0; acc[0][1] += a.x * b1; acc[0][2] += a.x * b2;
            acc[1][0] += a.y * b0; acc[1][1] += a.y * b1; acc[1][2] += a.y * b2;
        }
        __syncthreads();
    }
    float bv0 = bb[colbase + tx * 3], bv1 = bb[colbase + tx * 3 + 1], bv2 = bb[colbase + tx * 3 + 2];
    #pragma unroll
    for (int r = 0; r < 2; r++) {
        float* o = tmp + (size_t)(n0 + ty * 2 + r) * TMPW + f0 + tx * 3;
        o[0] = acc[r][0] + bv0; o[1] = acc[r][1] + bv1; o[2] = acc[r][2] + bv2;
    }
}

// ---------------- rotate point projections to global frame, in place on tmp
__global__ void rotate_kernel(const float* __restrict__ rot, const float* __restrict__ tran,
                              float* __restrict__ tmp)
{
    int pid = blockIdx.x * 256 + threadIdx.x;   // 512*192 points
    int n = pid / 192, q = pid % 192;
    float* p = tmp + (size_t)n * TMPW + 576 + q * 3;
    float v0 = p[0], v1 = p[1], v2 = p[2];
    const float* R = rot + n * 9;
    const float* T = tran + n * 3;
    p[0] = R[0] * v0 + R[1] * v1 + R[2] * v2 + T[0];
    p[1] = R[3] * v0 + R[4] * v1 + R[5] * v2 + T[1];
    p[2] = R[6] * v0 + R[7] * v1 + R[8] * v2 + T[2];
}

// ---------------- fused logits + softmax: one block per i, z pass 1
// attn[i][h][j] normalized written out.
__global__ void logits_softmax_kernel(const float* __restrict__ z, const float* __restrict__ resm,
                                      const float* __restrict__ Wsb, const float* __restrict__ bsb,
                                      const float* __restrict__ watt, const float* __restrict__ batt,
                                      const float* __restrict__ tpw, const float* __restrict__ tmp,
                                      float* __restrict__ attn)
{
    int i = blockIdx.x;
    __shared__ float zt[64 * 132];      // 33.8 KB
    __shared__ float lt[HH * NN];       // 24.6 KB  all logits for row i
    __shared__ float wt[HH * 136];      // scaled Wsb^T, stride 136 (aligned + conflict-free)
    __shared__ float sqs[192];
    __shared__ float pqi[144];
    __shared__ float cpt[12];
    __shared__ float cb[12];
    int tid = threadIdx.x;
    float w0 = watt[0], w1 = watt[1], w2 = watt[2], ba = batt[0];
    float A2 = w2 * ZW;

    for (int k = tid; k < 1536; k += 256) {
        int c = k / 12, h = k % 12;                 // read Wsb coalesced
        wt[h * 136 + c] = Wsb[k] * A2;
    }
    for (int k = tid; k < 192; k += 256) sqs[k] = tmp[(size_t)i * TMPW + k] * (SW * w0);
    if (tid < 144) pqi[tid] = tmp[(size_t)i * TMPW + 576 + tid];
    if (tid < 12) {
        cpt[tid] = -0.5f * log1pf(expf(tpw[tid])) * PW * w1;
        cb[tid]  = A2 * bsb[tid] + ba;
    }
    __syncthreads();

    int jl = tid >> 2, hg = tid & 3, h0 = hg * 3;
    float rmi = resm[i];

    for (int jt = 0; jt < 8; jt++) {
        int j0 = jt * 64;
        const float4* z4 = (const float4*)(z + ((size_t)i * NN + j0) * CZ);
        for (int k = tid; k < 2048; k += 256) {
            int r = k >> 5, c4 = k & 31;
            *(float4*)&zt[r * 132 + c4 * 4] = z4[k];
        }
        __syncthreads();

        int j = j0 + jl;
        float mj = rmi * resm[j];
        float p0 = cb[h0], p1 = cb[h0 + 1], p2 = cb[h0 + 2];
        const float* zr = &zt[jl * 132];
        const float* u0p = &wt[(h0 + 0) * 136];
        const float* u1p = &wt[(h0 + 1) * 136];
        const float* u2p = &wt[(h0 + 2) * 136];
        #pragma unroll 8
        for (int c = 0; c < 128; c += 4) {
            float4 zv = *(const float4*)&zr[c];
            float4 u0 = *(const float4*)&u0p[c];
            float4 u1 = *(const float4*)&u1p[c];
            float4 u2 = *(const float4*)&u2p[c];
            p0 += zv.x * u0.x + zv.y * u0.y + zv.z * u0.z + zv.w * u0.w;
            p1 += zv.x * u1.x + zv.y * u1.y + zv.z * u1.z + zv.w * u1.w;
            p2 += zv.x * u2.x + zv.y * u2.y + zv.z * u2.z + zv.w * u2.w;
        }

        #pragma unroll
        for (int t = 0; t < 3; t++) {
            int h = h0 + t;
            const float4* skp = (const float4*)(tmp + (size_t)j * TMPW + 192 + h * 16);
            const float* sqp = &sqs[h * 16];
            float d0 = 0.f;
            #pragma unroll
            for (int q = 0; q < 4; q++) {
                float4 kv = skp[q];
                d0 += sqp[q*4+0]*kv.x + sqp[q*4+1]*kv.y + sqp[q*4+2]*kv.z + sqp[q*4+3]*kv.w;
            }
            const float4* pkp = (const float4*)(tmp + (size_t)j * TMPW + 720 + h * 12);
            const float* pqp = &pqi[h * 12];
            float sd = 0.f;
            #pragma unroll
            for (int q = 0; q < 3; q++) {
                float4 kv = pkp[q];
                float a = pqp[q*4+0]-kv.x, b = pqp[q*4+1]-kv.y, c = pqp[q*4+2]-kv.z, e = pqp[q*4+3]-kv.w;
                sd += a*a + b*b + c*c + e*e;
            }
            float pairv = (t == 0) ? p0 : ((t == 1) ? p1 : p2);
            float lg = pairv + d0 + cpt[h] * sd;
            if (mj == 0.f) lg = NEG_INF;
            lt[h * NN + j] = lg;
        }
        __syncthreads();
    }

    // softmax over j for each head; write normalized attn to global
    int wid = tid >> 6, lane = tid & 63;
    for (int t = 0; t < 3; t++) {
        int h = wid + 4 * t;
        float* row = &lt[h * NN];
        float v[8]; float m = -INFINITY;
        #pragma unroll
        for (int u = 0; u < 8; u++) { v[u] = row[lane + 64 * u]; m = fmaxf(m, v[u]); }
        for (int off = 32; off; off >>= 1) m = fmaxf(m, __shfl_xor(m, off));
        float ssum = 0.f;
        #pragma unroll
        for (int u = 0; u < 8; u++) { v[u] = __expf(v[u] - m); ssum += v[u]; }
        for (int off = 32; off; off >>= 1) ssum += __shfl_xor(ssum, off);
        float inv = 1.f / ssum;
        float* ag = attn + ((size_t)i * HH + h) * NN;
        #pragma unroll
        for (int u = 0; u < 8; u++) ag[lane + 64 * u] = v[u] * inv;
    }
}

// ---------------- r_pair partials: z pass 2. grid (2 j-halves, 512 i)
// wave -> 64 j, all 12 heads; lane -> channels (2*lane, 2*lane+1)
__global__ void rpair_kernel(const float* __restrict__ z, const float* __restrict__ attn,
                             float* __restrict__ part)
{
    int jh = blockIdx.x;
    int i  = blockIdx.y;
    __shared__ float at[HH * 260];          // un-transposed P, pad 260
    __shared__ float pslab[4 * HH * 128];   // per-wave partials
    int tid = threadIdx.x;

    for (int k = tid; k < HH * 256; k += 256) {
        int h = k >> 8, jr = k & 255;
        at[h * 260 + jr] = attn[((size_t)i * HH + h) * NN + jh * 256 + jr];
    }
    __syncthreads();

    int wid = tid >> 6, lane = tid & 63;
    int c0 = lane * 2;
    const float* zb = z + ((size_t)i * NN + jh * 256 + wid * 64) * CZ;
    int pbase = wid * 64;
    float acc[HH][2];
    #pragma unroll
    for (int h = 0; h < HH; h++) { acc[h][0] = 0.f; acc[h][1] = 0.f; }

    #pragma unroll 4
    for (int jj = 0; jj < 64; jj++) {
        float2 zv = *(const float2*)&zb[(size_t)jj * CZ + c0];
        #pragma unroll
        for (int h = 0; h < HH; h++) {
            float p = at[h * 260 + pbase + jj];
            acc[h][0] += p * zv.x; acc[h][1] += p * zv.y;
        }
    }
    #pragma unroll
    for (int h = 0; h < HH; h++)
        *(float2*)&pslab[(wid * HH + h) * 128 + c0] = make_float2(acc[h][0], acc[h][1]);
    __syncthreads();

    // reduce 4 waves -> part[jh*512 + i][h*128+c]
    for (int k = tid; k < HH * 128; k += 256) {
        float ssum = pslab[k] + pslab[HH * 128 + k] + pslab[2 * HH * 128 + k] + pslab[3 * HH * 128 + k];
        part[((size_t)jh * NN + i) * (HH * 128) + k] = ssum;
    }
}

// ---------------- combine r_pair halves into cat
__global__ void combine_rpair_kernel(const float* __restrict__ part, float* __restrict__ cat)
{
    int v = blockIdx.x * 256 + threadIdx.x;     // 512*1536
    int i = v / (HH * 128), hc = v % (HH * 128);
    int h = hc >> 7, c = hc & 127;
    float ssum = part[(size_t)i * (HH * 128) + hc] + part[((size_t)NN + i) * (HH * 128) + hc];
    cat[(size_t)i * CATDIM + h * CATH + 48 + c] = ssum;
}

// ---------------- per-head r_scalar + r_pt (+rotate back, norm)
__global__ void head_sum_kernel(const float* __restrict__ attn, const float* __restrict__ tmp,
                                const float* __restrict__ rot, const float* __restrict__ tran,
                                float* __restrict__ cat)
{
    int i0 = blockIdx.x * 32;
    int h  = blockIdx.y;
    __shared__ float At[32][65];
    __shared__ float Sr[64][44];
    __shared__ float Rp[32][24];
    int tid = threadIdx.x;
    int il = tid & 31, fg = tid >> 5;
    float acc[5] = {0,0,0,0,0};

    for (int jc = 0; jc < NN; jc += 64) {
        {
            int r = tid >> 3, c8 = (tid & 7) * 8;
            const float* src = attn + ((size_t)(i0 + r) * HH + h) * NN + jc + c8;
            float4 v0 = *(const float4*)src;
            float4 v1 = *(const float4*)(src + 4);
            At[r][c8+0]=v0.x; At[r][c8+1]=v0.y; At[r][c8+2]=v0.z; At[r][c8+3]=v0.w;
            At[r][c8+4]=v1.x; At[r][c8+5]=v1.y; At[r][c8+6]=v1.z; At[r][c8+7]=v1.w;
        }
        {
            int jr = tid >> 2, d4 = (tid & 3) * 4;
            *(float4*)&Sr[jr][d4] = *(const float4*)&tmp[(size_t)(jc + jr) * TMPW + 384 + h * 16 + d4];
        }
        for (int e = tid; e < 384; e += 256) {
            int jr = e / 6, p4 = (e % 6) * 4;
            *(float4*)&Sr[jr][16 + p4] = *(const float4*)&tmp[(size_t)(jc + jr) * TMPW + 864 + h * 24 + p4];
        }
        __syncthreads();
        #pragma unroll 4
        for (int j = 0; j < 64; j++) {
            float a = At[il][j];
            #pragma unroll
            for (int q = 0; q < 5; q++) acc[q] += a * Sr[j][fg * 5 + q];
        }
        __syncthreads();
    }

    float* cbase = cat + (size_t)(i0 + il) * CATDIM + h * CATH;
    #pragma unroll
    for (int q = 0; q < 5; q++) {
        int f = fg * 5 + q;
        if (f < 16) cbase[f] = acc[q];
        else Rp[il][f - 16] = acc[q];
    }
    __syncthreads();

    {
        int il2 = tid >> 3, p = tid & 7;
        int i = i0 + il2;
        float gx = Rp[il2][p * 3 + 0] - tran[i * 3 + 0];
        float gy = Rp[il2][p * 3 + 1] - tran[i * 3 + 1];
        float gz = Rp[il2][p * 3 + 2] - tran[i * 3 + 2];
        const float* R = rot + i * 9;
        float lx = R[0] * gx + R[3] * gy + R[6] * gz;
        float ly = R[1] * gx + R[4] * gy + R[7] * gz;
        float lz = R[2] * gx + R[5] * gy + R[8] * gz;
        float nrm = sqrtf(lx * lx + ly * ly + lz * lz + 1e-8f);
        float* cp = cat + (size_t)i * CATDIM + h * CATH;
        cp[16 + p * 3 + 0] = lx; cp[16 + p * 3 + 1] = ly; cp[16 + p * 3 + 2] = lz;
        cp[40 + p] = nrm;
    }
}

// ---------------- out GEMM, K-split
__global__ void out_gemm_split_kernel(const float* __restrict__ cat, const float* __restrict__ Wout,
                                      float* __restrict__ part)
{
    int n0 = blockIdx.x * 64;
    int i0 = blockIdx.y * 64;
    int ks = blockIdx.z * KSPL;
    __shared__ float St[32][68];
    __shared__ float Bs[32][68];
    int tid = threadIdx.x;
    int ty = tid >> 4, tx = tid & 15;
    float acc[4][4] = {{0,0,0,0},{0,0,0,0},{0,0,0,0},{0,0,0,0}};

    for (int k0 = 0; k0 < KSPL; k0 += 32) {
        {
            int r = tid >> 2, c8 = (tid & 3) * 8;
            const float* src = cat + (size_t)(i0 + r) * CATDIM + ks + k0 + c8;
            float4 v0 = *(const float4*)src;
            float4 v1 = *(const float4*)(src + 4);
            St[c8+0][r]=v0.x; St[c8+1][r]=v0.y; St[c8+2][r]=v0.z; St[c8+3][r]=v0.w;
            St[c8+4][r]=v1.x; St[c8+5][r]=v1.y; St[c8+6][r]=v1.z; St[c8+7][r]=v1.w;
        }
        {
            int r = tid >> 3, c8 = (tid & 7) * 8;
            const float* src = Wout + (size_t)(ks + k0 + r) * CSD + n0 + c8;
            *(float4*)&Bs[r][c8]     = *(const float4*)src;
            *(float4*)&Bs[r][c8 + 4] = *(const float4*)(src + 4);
        }
        __syncthreads();
        #pragma unroll
        for (int k = 0; k < 32; k++) {
            float4 a = *(const float4*)&St[k][ty * 4];
            float4 b = *(const float4*)&Bs[k][tx * 4];
            float av[4] = {a.x, a.y, a.z, a.w};
            float bv[4] = {b.x, b.y, b.z, b.w};
            #pragma unroll
            for (int r = 0; r < 4; r++)
                #pragma unroll
                for (int c = 0; c < 4; c++) acc[r][c] += av[r] * bv[c];
        }
        __syncthreads();
    }
    #pragma unroll
    for (int r = 0; r < 4; r++) {
        float4 v = make_float4(acc[r][0], acc[r][1], acc[r][2], acc[r][3]);
        *(float4*)&part[((size_t)blockIdx.z * NN + i0 + ty * 4 + r) * CSD + n0 + tx * 4] = v;
    }
}

__global__ void reduce_out_kernel(const float* __restrict__ part, const float* __restrict__ bout,
                                  float* __restrict__ out)
{
    int v = blockIdx.x * 256 + threadIdx.x;
    int n4 = v % 96;
    float4 o = ((const float4*)bout)[n4];
    const float4* p4 = (const float4*)part;
    #pragma unroll
    for (int s = 0; s < NSPLIT; s++) {
        float4 t = p4[(size_t)s * 49152 + v];
        o.x += t.x; o.y += t.y; o.z += t.z; o.w += t.w;
    }
    ((float4*)out)[v] = o;
}

extern "C" void kernel_launch(void* const* d_in, const int* in_sizes, int n_in,
                              void* d_out, int out_size, void* d_ws, size_t ws_size,
                              hipStream_t stream) {
    const float* s    = (const float*)d_in[0];
    const float* z    = (const float*)d_in[1];
    const float* rot  = (const float*)d_in[2];
    const float* tran = (const float*)d_in[3];
    const float* resm = (const float*)d_in[4];
    const float* Wsq  = (const float*)d_in[5];  const float* bsq = (const float*)d_in[6];
    const float* Wsk  = (const float*)d_in[7];  const float* bsk = (const float*)d_in[8];
    const float* Wsv  = (const float*)d_in[9];  const float* bsv = (const float*)d_in[10];
    const float* Wsb  = (const float*)d_in[11]; const float* bsb = (const float*)d_in[12];
    const float* Wpq  = (const float*)d_in[13]; const float* bpq = (const float*)d_in[14];
    const float* Wpk  = (const float*)d_in[15]; const float* bpk = (const float*)d_in[16];
    const float* Wpv  = (const float*)d_in[17]; const float* bpv = (const float*)d_in[18];
    const float* watt = (const float*)d_in[19]; const float* batt = (const float*)d_in[20];
    const float* tpw  = (const float*)d_in[21];
    const float* Wout = (const float*)d_in[22]; const float* bout = (const float*)d_in[23];
    float* out = (float*)d_out;
    float* ws  = (float*)d_ws;

    float* tmp    = ws;                      // 512*1152   = 589824
    float* attn   = tmp + 589824;            // 512*12*512 = 3145728
    float* cat    = attn + 3145728;          // 512*2112   = 1081344
    float* partO  = cat + 1081344;           // 6*512*384  = 1179648
    float* partR  = partO + 1179648;         // 2*512*1536 = 1572864

    proj_gemm_kernel<<<dim3(24, 16), 256, 0, stream>>>(s, Wsq, bsq, Wsk, bsk, Wsv, bsv,
                                                       Wpq, bpq, Wpk, bpk, Wpv, bpv, tmp);
    rotate_kernel<<<384, 256, 0, stream>>>(rot, tran, tmp);
    logits_softmax_kernel<<<512, 256, 0, stream>>>(z, resm, Wsb, bsb, watt, batt, tpw,
                                                   tmp, attn);
    rpair_kernel<<<dim3(2, 512), 256, 0, stream>>>(z, attn, partR);
    combine_rpair_kernel<<<3072, 256, 0, stream>>>(partR, cat);
    head_sum_kernel<<<dim3(16, 12), 256, 0, stream>>>(attn, tmp, rot, tran, cat);
    out_gemm_split_kernel<<<dim3(6, 8, NSPLIT), 256, 0, stream>>>(cat, Wout, partO);
    reduce_out_kernel<<<192, 256, 0, stream>>>(partO, bout, out);
}